// Round 1
// baseline (103.226 us; speedup 1.0000x reference)
//
#include <hip/hip_runtime.h>

#define FLT_MAX_ 3.402823466e+38f

constexpr int PARTS = 8;        // waves per workgroup (K-dim parts)
constexpr int CB    = 4;        // channels per part (32/8)
constexpr int HW    = 9216;     // 96*96
constexpr int TPB   = 64 * PARTS;

__global__ __launch_bounds__(512)
void sac_fused(const float* __restrict__ x,
               const float* __restrict__ fc1_w, const float* __restrict__ fc1_b,
               const float* __restrict__ alpha_w, const float* __restrict__ alpha_b,
               const float* __restrict__ phi_w, const float* __restrict__ phi_b,
               const float* __restrict__ bn_g, const float* __restrict__ bn_b,
               const float* __restrict__ bn_m, const float* __restrict__ bn_v,
               float* __restrict__ out)
{
    __shared__ float    h_lds[64 * 65];     // [pos][k], pad 65 -> bank (i+k)%32
    __shared__ unsigned cnts[16 * 64];      // [bin][pos]   bank = pos%32
    __shared__ float    redS[TPB], redMn[TPB], redMx[TPB];
    __shared__ float    redS2[TPB], redS3[TPB], redS4[TPB], redP[TPB];
    __shared__ float    stats_lds[64 * 5];  // [pos][mu,sig,gam,kap,ent]

    const int tid  = threadIdx.x;
    const int lane = tid & 63;                                    // = position in tile
    const int w    = __builtin_amdgcn_readfirstlane(tid >> 6);    // wave-uniform part id
    const int g    = blockIdx.x;
    const int b    = g / 144;
    const int l0   = (g - b * 144) * 64;
    const int l    = l0 + lane;
    const int row  = l / 96;
    const int col  = l - row * 96;

    // zero histogram (1024 u32)
    cnts[tid] = 0u;
    cnts[tid + TPB] = 0u;

    const float* __restrict__ xp = x + ((size_t)b * 32 + (size_t)w * CB) * HW;

    // ---------------- pass 1: sum / min / max over this part's 36 taps ----------------
    float sum = 0.f, mn = FLT_MAX_, mx = -FLT_MAX_;
    for (int cc = 0; cc < CB; ++cc) {
        const float* __restrict__ xc = xp + (size_t)cc * HW;
        #pragma unroll
        for (int dy = 0; dy < 3; ++dy) {
            const int y = row + dy - 1;
            const bool yin = (unsigned)y < 96u;
            #pragma unroll
            for (int dx = 0; dx < 3; ++dx) {
                const int xx = col + dx - 1;
                const float p = (yin && ((unsigned)xx < 96u)) ? xc[y * 96 + xx] : 0.f;
                sum += p;
                mn = fminf(mn, p);
                mx = fmaxf(mx, p);
            }
        }
    }
    redS [w * 64 + lane] = sum;
    redMn[w * 64 + lane] = mn;
    redMx[w * 64 + lane] = mx;
    __syncthreads();

    float tsum = 0.f, tmn = FLT_MAX_, tmx = -FLT_MAX_;
    #pragma unroll
    for (int r = 0; r < PARTS; ++r) {
        tsum += redS[r * 64 + lane];
        tmn = fminf(tmn, redMn[r * 64 + lane]);
        tmx = fmaxf(tmx, redMx[r * 64 + lane]);
    }
    const float mu  = tsum / 288.0f;
    const float rng = (tmx - tmn) + 1e-6f;   // matches ref fp32 exactly (min/max order-free)

    // ---------------- pass 2: central moments + histogram ----------------
    float s2 = 0.f, s3 = 0.f, s4 = 0.f;
    for (int cc = 0; cc < CB; ++cc) {
        const float* __restrict__ xc = xp + (size_t)cc * HW;
        #pragma unroll
        for (int dy = 0; dy < 3; ++dy) {
            const int y = row + dy - 1;
            const bool yin = (unsigned)y < 96u;
            #pragma unroll
            for (int dx = 0; dx < 3; ++dx) {
                const int xx = col + dx - 1;
                const float p = (yin && ((unsigned)xx < 96u)) ? xc[y * 96 + xx] : 0.f;
                const float d  = p - mu;
                const float d2 = d * d;
                s2 += d2; s3 += d2 * d; s4 += d2 * d2;
                // IEEE division so the bin decision bit-matches the reference
                const float pn = (p - tmn) / rng;
                int bi = (int)(pn * 15.0f);
                bi = bi < 0 ? 0 : (bi > 15 ? 15 : bi);
                atomicAdd(&cnts[bi * 64 + lane], 1u);
            }
        }
    }
    redS2[w * 64 + lane] = s2;
    redS3[w * 64 + lane] = s3;
    redS4[w * 64 + lane] = s4;
    __syncthreads();

    // ---------------- finalize stats (wave 0; lane = position) ----------------
    if (w == 0) {
        float u2 = 0.f, u3 = 0.f, u4 = 0.f;
        #pragma unroll
        for (int r = 0; r < PARTS; ++r) {
            u2 += redS2[r * 64 + lane];
            u3 += redS3[r * 64 + lane];
            u4 += redS4[r * 64 + lane];
        }
        const float var  = u2 / 288.0f;
        const float sig  = sqrtf(var + 1e-6f);
        const float inv  = 1.0f / (sig + 1e-6f);
        const float inv2 = inv * inv;
        const float gam  = (u3 * (inv2 * inv)) / 288.0f;
        const float kap  = (u4 * (inv2 * inv2)) / 288.0f - 3.0f;
        float ent = 0.f;
        #pragma unroll
        for (int bi = 0; bi < 16; ++bi) {
            const float prob = (float)cnts[bi * 64 + lane] / 288.0f;
            ent -= prob * logf(prob + 1e-9f);
        }
        stats_lds[lane * 5 + 0] = mu;
        stats_lds[lane * 5 + 1] = sig;
        stats_lds[lane * 5 + 2] = gam;
        stats_lds[lane * 5 + 3] = kap;
        stats_lds[lane * 5 + 4] = ent;
    }
    __syncthreads();

    // ---------------- h = relu(stats @ fc1_w^T + fc1_b) -> LDS ----------------
    #pragma unroll
    for (int r = 0; r < 4096 / TPB; ++r) {
        const int idx = tid + r * TPB;
        const int pp_ = idx >> 6;       // position (wave-uniform in value)
        const int k   = idx & 63;
        float acc = fc1_b[k];
        #pragma unroll
        for (int s5 = 0; s5 < 5; ++s5)
            acc += stats_lds[pp_ * 5 + s5] * fc1_w[k * 5 + s5];
        h_lds[pp_ * 65 + k] = fmaxf(acc, 0.f);
    }
    __syncthreads();

    // ---------------- t[k] = sum_j p[j]*phi_w[j,k]  (s_load-fed FMA) ----------------
    float t[64];
    #pragma unroll
    for (int k = 0; k < 64; ++k) t[k] = 0.f;
    float pb_acc = 0.f;
    for (int cc = 0; cc < CB; ++cc) {
        const float* __restrict__ xc = xp + (size_t)cc * HW;
        const int jb = (w * CB + cc) * 9;   // wave-uniform
        #pragma unroll
        for (int dy = 0; dy < 3; ++dy) {
            const int y = row + dy - 1;
            const bool yin = (unsigned)y < 96u;
            #pragma unroll
            for (int dx = 0; dx < 3; ++dx) {
                const int xx = col + dx - 1;
                const float p = (yin && ((unsigned)xx < 96u)) ? xc[y * 96 + xx] : 0.f;
                const int j = jb + dy * 3 + dx;                     // uniform
                const float* __restrict__ pw = phi_w + j * 64;      // uniform -> s_load
                pb_acc = fmaf(p, phi_b[j], pb_acc);
                #pragma unroll
                for (int k = 0; k < 64; ++k)
                    t[k] = fmaf(p, pw[k], t[k]);
            }
        }
    }

    // ---------------- proj partial = phi_b.p + h.t ----------------
    float projp = pb_acc;
    #pragma unroll
    for (int k = 0; k < 64; ++k)
        projp += h_lds[lane * 65 + k] * t[k];
    redP[w * 64 + lane] = projp;
    __syncthreads();
    float proj = 0.f;
    #pragma unroll
    for (int r = 0; r < PARTS; ++r) proj += redP[r * 64 + lane];

    // ---------------- alpha (8 output channels per part) + BN + SiLU ----------------
    float acc8[8];
    #pragma unroll
    for (int cj = 0; cj < 8; ++cj) acc8[cj] = 0.f;
    for (int k = 0; k < 64; ++k) {
        const float hk = h_lds[lane * 65 + k];
        #pragma unroll
        for (int cj = 0; cj < 8; ++cj)
            acc8[cj] = fmaf(hk, alpha_w[(w * 8 + cj) * 64 + k], acc8[cj]);  // uniform -> s_load
    }
    #pragma unroll
    for (int cj = 0; cj < 8; ++cj) {
        const int c = w * 8 + cj;
        const float a    = acc8[cj] + alpha_b[c];
        const float o    = a * proj;
        const float binv = bn_g[c] / sqrtf(bn_v[c] + 1e-5f);
        const float yv   = (o - bn_m[c]) * binv + bn_b[c];
        const float sv   = yv / (1.0f + expf(-yv));   // silu
        out[((size_t)(b * 64 + c)) * HW + (size_t)(l0 + lane)] = sv;
    }
}

extern "C" void kernel_launch(void* const* d_in, const int* in_sizes, int n_in,
                              void* d_out, int out_size, void* d_ws, size_t ws_size,
                              hipStream_t stream) {
    const float* x   = (const float*)d_in[0];
    const float* f1w = (const float*)d_in[1];
    const float* f1b = (const float*)d_in[2];
    const float* aw  = (const float*)d_in[3];
    const float* ab  = (const float*)d_in[4];
    const float* pw  = (const float*)d_in[5];
    const float* pb  = (const float*)d_in[6];
    const float* bg  = (const float*)d_in[7];
    const float* bb  = (const float*)d_in[8];
    const float* bm  = (const float*)d_in[9];
    const float* bv  = (const float*)d_in[10];

    sac_fused<<<dim3(576), dim3(512), 0, stream>>>(
        x, f1w, f1b, aw, ab, pw, pb, bg, bb, bm, bv, (float*)d_out);
}